// Round 6
// baseline (6184.007 us; speedup 1.0000x reference)
//
#include <hip/hip_runtime.h>
#include <math.h>

typedef _Float16 f16;
using f16x8 = __attribute__((ext_vector_type(8))) _Float16;
using f32x4 = __attribute__((ext_vector_type(4))) float;
using u32x4 = __attribute__((ext_vector_type(4))) unsigned;

// Problem sizes (fixed)
#define NB 64
#define NS 1024
#define NDIM 512
#define NH 512

// ws layout (bytes): xsB | w16 (Wi_f,Wh_f,Wi_b,Wh_b f16)
#define XSB_OFF   0ULL
#define W16_OFF   134217728ULL

__device__ inline float fast_tanh(float y) {
    // tanh(y) = 1 - 2/(exp2(2*log2e*y)+1); exact at both saturating tails.
    float t = __builtin_amdgcn_exp2f(y * 2.8853900817779268f);
    return 1.0f - 2.0f * __builtin_amdgcn_rcpf(t + 1.0f);
}

__device__ inline unsigned pack_hilo(float v) {
    f16 hi = (f16)v;
    f16 lo = (f16)(v - (float)hi);
    return ((unsigned)__builtin_bit_cast(unsigned short, lo) << 16) |
           (unsigned)__builtin_bit_cast(unsigned short, hi);
}
__device__ inline float unpack_sum(unsigned u) {
    unsigned short hb = (unsigned short)(u & 0xffffu);
    unsigned short lb = (unsigned short)(u >> 16);
    return (float)__builtin_bit_cast(f16, hb) + (float)__builtin_bit_cast(f16, lb);
}

// ---------------- weight conversion fp32 -> fp16 ----------------
__global__ __launch_bounds__(256) void cvt_w(const float* __restrict__ wi_f,
                                             const float* __restrict__ wh_f,
                                             const float* __restrict__ wi_b,
                                             const float* __restrict__ wh_b,
                                             f16* __restrict__ o) {
    int i = blockIdx.x * 256 + threadIdx.x;
    if (i < 512 * 512) {
        o[i]              = (f16)wi_f[i];
        o[262144 + i]     = (f16)wh_f[i];
        o[2 * 262144 + i] = (f16)wi_b[i];
        o[3 * 262144 + i] = (f16)wh_b[i];
    }
}

// ---------------- input projection GEMM ----------------
// xs[dir] = pack(x @ Wi^T + bi).  M=65536, N=512, K=512. 128x128 tile, BK=32.
#define PLDA 40  // padded row (f16 elems)

__global__ __launch_bounds__(256)
void proj(const float* __restrict__ x, const f16* __restrict__ w16base,
          const float* __restrict__ bi_f, const float* __restrict__ bi_b,
          unsigned* __restrict__ xsF, unsigned* __restrict__ xsB)
{
    __shared__ f16 Ah[128 * PLDA];
    __shared__ f16 Bh[128 * PLDA];

    int bidx = blockIdx.x;
    int dir = bidx >> 11;
    int rem = bidx & 2047;
    int mt = rem >> 2, nt = rem & 3;

    const f16* Wi16 = w16base + (dir ? 2 * 262144 : 0);
    const float* bi = dir ? bi_b : bi_f;
    unsigned* xs = dir ? xsB : xsF;

    int tid = threadIdx.x;
    int lane = tid & 63, w = tid >> 6;
    int wm = (w >> 1) * 64, wn = (w & 1) * 64;

    f32x4 acc[4][4] = {};

    for (int ks = 0; ks < 16; ++ks) {
        int k0 = ks * 32;
        for (int it = 0; it < 4; ++it) {
            int idx = tid + it * 256;
            int row = idx >> 3, slot = idx & 7;
            float4 v = *(const float4*)(x + (size_t)(mt * 128 + row) * 512 + k0 + slot * 4);
            f16* dst = Ah + row * PLDA + slot * 4;
            dst[0] = (f16)v.x; dst[1] = (f16)v.y; dst[2] = (f16)v.z; dst[3] = (f16)v.w;
        }
        for (int it = 0; it < 2; ++it) {
            int idx = tid + it * 256;
            int row = idx >> 2, slot = idx & 3;
            uint4 v = *(const uint4*)(Wi16 + (size_t)(nt * 128 + row) * 512 + k0 + slot * 8);
            *(uint4*)(Bh + row * PLDA + slot * 8) = v;
        }
        __syncthreads();

        f16x8 af[4], bf[4];
        for (int i = 0; i < 4; ++i) {
            int arow = wm + i * 16 + (lane & 15);
            af[i] = *(const f16x8*)(Ah + arow * PLDA + ((lane >> 4) * 8));
            int brow = wn + i * 16 + (lane & 15);
            bf[i] = *(const f16x8*)(Bh + brow * PLDA + ((lane >> 4) * 8));
        }
        for (int i = 0; i < 4; ++i)
            for (int j = 0; j < 4; ++j)
                acc[i][j] = __builtin_amdgcn_mfma_f32_16x16x32_f16(af[i], bf[j], acc[i][j], 0, 0, 0);
        __syncthreads();
    }

    for (int i = 0; i < 4; ++i) {
        for (int j = 0; j < 4; ++j) {
            int jg = nt * 128 + wn + j * 16 + (lane & 15);
            float bv = bi[jg];
            for (int r = 0; r < 4; ++r) {
                int mg = mt * 128 + wm + i * 16 + (lane >> 4) * 4 + r;
                xs[(size_t)mg * 512 + jg] = pack_hilo(acc[i][j][r] + bv);
            }
        }
    }
}

// ---------------- recurrence: whole ring inside ONE workgroup ----------------
// 16 WGs = 2 dir x 8 batch-groups of 8. 512 threads (8 waves, 2/SIMD).
// Each wave owns 64 j-cols: jf 0..2 register-resident (192 VGPR), jf 3 in LDS.
// h hi-f16 plane in LDS (16 rows; rows 8..15 zero). No cross-WG traffic.
#define WL_LDA 516   // Wh-LDS row stride (f16): 1032B
#define HP_LDA 520   // h-plane row stride (f16): 1040B
#define LDS_BYTES (128 * WL_LDA * 2 + 16 * HP_LDA * 2)   // 132096 + 16640 = 148736

__global__ __launch_bounds__(512, 2)
void rnn_rec(const float* __restrict__ h0, const f16* __restrict__ w16base,
             const float* __restrict__ bh_f, const float* __restrict__ bh_b,
             unsigned* __restrict__ xsF, unsigned* __restrict__ xsB)
{
    extern __shared__ char smem[];
    f16* whl = (f16*)smem;                         // 128 rows x WL_LDA
    f16* hp  = (f16*)(smem + 128 * WL_LDA * 2);    // 16 rows x HP_LDA

    int bid = blockIdx.x;          // 0..15
    int dir = bid >> 3, g = bid & 7;
    unsigned* xsu = dir ? xsB : xsF;
    const f16* Wh16 = w16base + 262144 + (dir ? 2 * 262144 : 0);
    const float* bh = dir ? bh_b : bh_f;
    int b0 = g * 8;

    int tid = threadIdx.x, lane = tid & 63, w = tid >> 6;   // w 0..7
    int l15 = lane & 15, lhi = lane >> 4;                    // lhi 0..3
    int wj0 = w * 64;

    // ---- Wh register fragments: jf 0..2 (cols wj0 .. wj0+47) ----
    f16x8 bf0[16], bf1[16], bf2[16];
    {
        const f16* r0 = Wh16 + (size_t)(wj0      + l15) * 512 + lhi * 8;
        const f16* r1 = Wh16 + (size_t)(wj0 + 16 + l15) * 512 + lhi * 8;
        const f16* r2 = Wh16 + (size_t)(wj0 + 32 + l15) * 512 + lhi * 8;
        #pragma unroll
        for (int kc = 0; kc < 16; ++kc) {
            bf0[kc] = *(const f16x8*)(r0 + kc * 32);
            bf1[kc] = *(const f16x8*)(r1 + kc * 32);
            bf2[kc] = *(const f16x8*)(r2 + kc * 32);
        }
    }

    // ---- Wh LDS fragment: jf 3 (cols wj0+48 .. wj0+63) -> rows [w*16, +16) ----
    #pragma unroll
    for (int it = 0; it < 16; ++it) {
        int s = lane + it * 64;              // 0..1023: 16 rows x 64 slots
        int row = s >> 6, c8 = s & 63;
        *(f16x8*)(whl + (size_t)(w * 16 + row) * WL_LDA + c8 * 8) =
            *(const f16x8*)(Wh16 + (size_t)(wj0 + 48 + row) * 512 + c8 * 8);
    }

    // ---- h plane init: rows 0..7 = h0 (hi-f16), rows 8..15 = 0 ----
    #pragma unroll
    for (int it = 0; it < 16; ++it) {
        int idx = tid + it * 512;            // 0..8191: 16 rows x 512 cols
        int row = idx >> 9, c = idx & 511;
        f16 v = (f16)0.f;
        if (row < 8) v = (f16)h0[(size_t)(b0 + row) * 512 + c];
        hp[(size_t)row * HP_LDA + c] = v;
    }

    float bh0 = bh[wj0 + l15];
    float bh1 = bh[wj0 + 16 + l15];
    float bh2 = bh[wj0 + 32 + l15];
    float bh3 = bh[wj0 + 48 + l15];
    int rbase = lhi * 4;                     // C rows rbase..rbase+3
    bool valid = rbase < 8;                  // lanes 0..31 hold real batches

    const f16* arow  = hp + (size_t)l15 * HP_LDA + lhi * 8;
    const f16* brow3 = whl + (size_t)(w * 16 + l15) * WL_LDA + lhi * 8;

    __syncthreads();

    for (int st = 0; st < 1024; ++st) {
        int tt = dir ? 1023 - st : st;

        // xt prefetch (16 words on valid lanes); latency hides under MFMA
        unsigned xt0[4], xt1[4], xt2[4], xt3[4];
        if (valid) {
            #pragma unroll
            for (int r = 0; r < 4; ++r) {
                size_t base = ((size_t)(b0 + rbase + r) * 1024 + tt) * 512 + wj0 + l15;
                xt0[r] = xsu[base];
                xt1[r] = xsu[base + 16];
                xt2[r] = xsu[base + 32];
                xt3[r] = xsu[base + 48];
            }
        }

        f32x4 a0 = {0.f,0.f,0.f,0.f}, a1 = {0.f,0.f,0.f,0.f};
        f32x4 a2 = {0.f,0.f,0.f,0.f}, a3 = {0.f,0.f,0.f,0.f};

        #pragma unroll
        for (int kc = 0; kc < 16; ++kc) {
            f16x8 a = *(const f16x8*)(arow + kc * 32);
            f16x8 b3 = *(const f16x8*)(brow3 + kc * 32);
            a0 = __builtin_amdgcn_mfma_f32_16x16x32_f16(a, bf0[kc], a0, 0, 0, 0);
            a1 = __builtin_amdgcn_mfma_f32_16x16x32_f16(a, bf1[kc], a1, 0, 0, 0);
            a2 = __builtin_amdgcn_mfma_f32_16x16x32_f16(a, bf2[kc], a2, 0, 0, 0);
            a3 = __builtin_amdgcn_mfma_f32_16x16x32_f16(a, b3,      a3, 0, 0, 0);
        }
        __syncthreads();     // all reads of hp(t-1) complete

        if (valid) {
            #pragma unroll
            for (int r = 0; r < 4; ++r) {
                size_t obase = ((size_t)(b0 + rbase + r) * 1024 + tt) * 512 + wj0 + l15;
                size_t prow = (size_t)(rbase + r) * HP_LDA + wj0 + l15;
                float h0v = fast_tanh(a0[r] + unpack_sum(xt0[r]) + bh0);
                float h1v = fast_tanh(a1[r] + unpack_sum(xt1[r]) + bh1);
                float h2v = fast_tanh(a2[r] + unpack_sum(xt2[r]) + bh2);
                float h3v = fast_tanh(a3[r] + unpack_sum(xt3[r]) + bh3);
                hp[prow]      = (f16)h0v;
                hp[prow + 16] = (f16)h1v;
                hp[prow + 32] = (f16)h2v;
                hp[prow + 48] = (f16)h3v;
                xsu[obase]      = pack_hilo(h0v);   // plain fire-and-forget
                xsu[obase + 16] = pack_hilo(h1v);
                xsu[obase + 32] = pack_hilo(h2v);
                xsu[obase + 48] = pack_hilo(h3v);
            }
        }
        __syncthreads();     // hp(t) complete for all waves
    }
}

// ---------------- merge: out = h_f + h_b (both stored packed hi/lo) ----------------
__global__ __launch_bounds__(256)
void merge_out(const u32x4* __restrict__ xsF, const u32x4* __restrict__ xsB,
               float* __restrict__ out)
{
    size_t i = (size_t)blockIdx.x * 256 + threadIdx.x;
    size_t stride = (size_t)gridDim.x * 256;
    for (; i < 8388608ULL; i += stride) {
        u32x4 a = xsF[i];
        u32x4 b = xsB[i];
        float4 o;
        o.x = unpack_sum(a.x) + unpack_sum(b.x);
        o.y = unpack_sum(a.y) + unpack_sum(b.y);
        o.z = unpack_sum(a.z) + unpack_sum(b.z);
        o.w = unpack_sum(a.w) + unpack_sum(b.w);
        *(float4*)(out + i * 4) = o;
    }
}

__global__ __launch_bounds__(256)
void copy_hidden(const float* __restrict__ hs, float* __restrict__ out)
{
    size_t i = (size_t)blockIdx.x * 256 + threadIdx.x;
    if (i < 32768) out[33554432ULL + i] = hs[i];
}

// ---------------- launch ----------------
extern "C" void kernel_launch(void* const* d_in, const int* in_sizes, int n_in,
                              void* d_out, int out_size, void* d_ws, size_t ws_size,
                              hipStream_t stream) {
    const float* x    = (const float*)d_in[0];
    const float* hs   = (const float*)d_in[1];
    const float* Wi_f = (const float*)d_in[2];
    const float* bi_f = (const float*)d_in[3];
    const float* Wh_f = (const float*)d_in[4];
    const float* bh_f = (const float*)d_in[5];
    const float* Wi_b = (const float*)d_in[6];
    const float* bi_b = (const float*)d_in[7];
    const float* Wh_b = (const float*)d_in[8];
    const float* bh_b = (const float*)d_in[9];

    float* out = (float*)d_out;
    char* ws = (char*)d_ws;

    unsigned* xsF = (unsigned*)out;             // forward history lives in d_out
    unsigned* xsB = (unsigned*)(ws + XSB_OFF);
    f16* w16      = (f16*)(ws + W16_OFF);

    cvt_w<<<1024, 256, 0, stream>>>(Wi_f, Wh_f, Wi_b, Wh_b, w16);
    proj<<<4096, 256, 0, stream>>>(x, w16, bi_f, bi_b, xsF, xsB);

    (void)hipFuncSetAttribute((const void*)rnn_rec,
                              hipFuncAttributeMaxDynamicSharedMemorySize, LDS_BYTES);
    rnn_rec<<<16, 512, LDS_BYTES, stream>>>(hs, w16, bh_f, bh_b, xsF, xsB);

    merge_out<<<2048, 256, 0, stream>>>((const u32x4*)xsF, (const u32x4*)xsB, out);
    copy_hidden<<<128, 256, 0, stream>>>(hs, out);
}